// Round 5
// baseline (50.189 us; speedup 1.0000x reference)
//
#include <hip/hip_runtime.h>
#include <hip/hip_bf16.h>

#define HRr 30
#define WRr 40
#define MM 1200      // HRr*WRr
#define CC 128
#define NB 8
#define GS 8

constexpr int PT = 19;                   // 64-col fragment tiles per dim (ws layout)
constexpr int TILE_SH = 16 * 64 * 8;     // shorts per (n,tile) fragment block = 8192
constexpr int NSTRIP = 75;               // 16-row strips per image
constexpr int NPART = NB * NSTRIP;       // 600 partial sums

typedef __attribute__((ext_vector_type(8))) short bf16x8;
typedef __attribute__((ext_vector_type(4))) float f32x4;

__device__ inline short f2bf(float f) {
    union { float f; unsigned u; } v; v.f = f;
    unsigned r = v.u + 0x7FFFu + ((v.u >> 16) & 1u);   // RNE
    return (short)(r >> 16);
}

// ------- Kernel A: fused {warped grid, reduced mask, f32->bf16 fragment convert} -------
// ws layout per (n, tile): [ks 0..3][rb 0..3][lane 0..63][8 halfwords]
// lane l = lr*16+lc holds (row = rb*16+lc, k = ks*32+lr*8 .. +7).
__global__ __launch_bounds__(256) void convert_prep_kernel(const float* __restrict__ des1,
                                                           const float* __restrict__ des2,
                                                           const float* __restrict__ homo,
                                                           const float* __restrict__ mask,
                                                           short* __restrict__ wsA,
                                                           short* __restrict__ wsB,
                                                           float2* __restrict__ wgrid,
                                                           float* __restrict__ out_rmask,
                                                           float* __restrict__ ws_rmask) {
    const int t     = threadIdx.x;
    const int ptile = blockIdx.x;      // 0..18
    const int n     = blockIdx.z;      // 0..7

    // ---- prep part (first 9600 threads of the 38912-thread grid) ----
    const int gid = (blockIdx.z * gridDim.x + blockIdx.x) * 256 + t;
    if (gid < MM) {
        int k = gid / WRr, l = gid % WRr;
        float x = (float)(l * GS + GS / 2);
        float y = (float)(k * GS + GS / 2);
        float nx = homo[0] * x + homo[1] * y + homo[2];
        float ny = homo[3] * x + homo[4] * y + homo[5];
        float dn = homo[6] * x + homo[7] * y + homo[8];
        wgrid[gid] = make_float2(nx / dn, ny / dn);
    }
    if (gid < NB * MM) {
        int nn = gid / MM;
        int rem = gid % MM;
        int k = rem / WRr, l = rem % WRr;
        const float* mp = mask + (size_t)nn * (240 * 320) + (size_t)(k * GS) * 320 + l * GS;
        float prod = 1.f;
        #pragma unroll
        for (int yy = 0; yy < GS; ++yy) {
            float4 a = *reinterpret_cast<const float4*>(&mp[yy * 320]);
            float4 b = *reinterpret_cast<const float4*>(&mp[yy * 320 + 4]);
            prod *= a.x * a.y * a.z * a.w * b.x * b.y * b.z * b.w;
        }
        out_rmask[gid] = prod;
        ws_rmask[gid]  = prod;
    }

    // ---- convert part ----
    const int j = t & 63;              // row within tile
    const int g = t >> 6;              // wave id = k-run group
    const int p = ptile * 64 + j;

    const float* A = des1 + (size_t)n * CC * MM;
    const float* B = des2 + (size_t)n * CC * MM;
    short* outA = wsA + (size_t)(n * PT + ptile) * TILE_SH;
    short* outB = wsB + (size_t)(n * PT + ptile) * TILE_SH;

    const int rb = j >> 4, lc = j & 15;
    #pragma unroll
    for (int it = 0; it < 4; ++it) {
        const int kr = it * 4 + g;          // k-run index 0..15
        const int kb = kr * 8;
        bf16x8 wa, wb;
        #pragma unroll
        for (int i = 0; i < 8; ++i) {
            float va = (p < MM) ? A[(size_t)(kb + i) * MM + p] : 0.f;  // coalesced per i
            float vb = (p < MM) ? B[(size_t)(kb + i) * MM + p] : 0.f;
            wa[i] = f2bf(va);
            wb[i] = f2bf(vb);
        }
        const int ks = kr >> 2, lr = kr & 3;
        const size_t off = (size_t)(((ks * 4 + rb) * 64) + lr * 16 + lc) * 8;
        *reinterpret_cast<bf16x8*>(&outA[off]) = wa;
        *reinterpret_cast<bf16x8*>(&outB[off]) = wb;
    }
}

// ---------------- Kernel B: strip MFMA GEMM + line-aligned epilogue ----------------
// Block = (n, 16-row strip), computes dot for all 1200 cols in 2 LDS half-passes.
// Write phase picks per-row line-aligned float4 windows -> no partial-line stores
// in the body (head/tail handled as scalars).
__global__ __launch_bounds__(256) void main_kernel(const short* __restrict__ wsA,
                                                   const short* __restrict__ wsB,
                                                   const float2* __restrict__ wgrid,
                                                   const float* __restrict__ rmask,
                                                   float* __restrict__ out_s,
                                                   float* __restrict__ out_dot,
                                                   float* __restrict__ partials) {
    __shared__ float Ds[16 * 612];    // strip half: 16 rows x (<=608 cols), +1 shift, stride 612
    __shared__ float red[4];

    const int f   = blockIdx.x;
    const int lid = (f & 7) * NSTRIP + (f >> 3);   // XCD-chunked: XCD k <- image n=k
    const int n     = lid / NSTRIP;
    const int strip = lid % NSTRIP;
    const int p0 = strip * 16;

    const int t    = threadIdx.x;
    const int lane = t & 63;
    const int w    = t >> 6;
    const int lr   = lane >> 4, lc = lane & 15;

    // A fragments for rows p0..p0+15, all 4 k-slices
    const short* An  = wsA + (size_t)(n * PT + (p0 >> 6)) * TILE_SH;
    const int    rbA = (p0 >> 4) & 3;
    bf16x8 af[4];
    #pragma unroll
    for (int ks = 0; ks < 4; ++ks)
        af[ks] = *reinterpret_cast<const bf16x8*>(&An[(size_t)(((ks * 4 + rbA) * 64) + lane) * 8]);

    const short* Bn = wsB + (size_t)n * PT * TILE_SH;
    const float* rm = rmask + n * MM;

    // write-phase geometry (each 16-lane group owns one row)
    const int row = t >> 4;
    const int l16 = t & 15;
    const int p   = p0 + row;
    const float gx = (float)((p % WRr) * GS + GS / 2);
    const float gy = (float)((p / WRr) * GS + GS / 2);
    const size_t rowbase = (size_t)(n * MM + p) * MM;
    const int h = 31 - 16 * (p & 1);   // cols to first 128B line boundary

    float lsum = 0.f;

    #pragma unroll
    for (int pass = 0; pass < 2; ++pass) {
        const int cbase = pass ? 608 : 0;
        const int nf    = pass ? 37  : 38;    // col-frags this pass
        const int W     = pass ? 592 : 608;   // cols this pass

        // ---- compute: each wave takes col-frags i = w, w+4, ... ----
        for (int i = w; i < nf; i += 4) {
            const int g = (cbase >> 4) + i;                 // global col-frag 0..74
            const short* Bt = Bn + (size_t)(g >> 2) * TILE_SH;
            const int rbB = g & 3;
            f32x4 acc = {0.f, 0.f, 0.f, 0.f};
            #pragma unroll
            for (int ks = 0; ks < 4; ++ks) {
                bf16x8 bfr = *reinterpret_cast<const bf16x8*>(
                    &Bt[(size_t)(((ks * 4 + rbB) * 64) + lane) * 8]);
                acc = __builtin_amdgcn_mfma_f32_16x16x32_bf16(af[ks], bfr, acc, 0, 0, 0);
            }
            #pragma unroll
            for (int r = 0; r < 4; ++r)
                Ds[(lr * 4 + r) * 612 + 1 + i * 16 + lc] = acc[r];   // D row=lr*4+r, col=lc
        }
        __syncthreads();

        // ---- write: head scalars, line-aligned float4 body, tail scalars ----
        const int nl = (W - h) >> 5;      // full 128B lines in body
        const int s4 = nl << 3;           // float4 slots
        const int ts = h + (nl << 5);     // tail start (rel col)

        for (int c = l16; c < h; c += 16) {
            const float dot = Ds[row * 612 + 1 + c];
            const int q = cbase + c;
            const float2 wg = wgrid[q];
            const float dx = gx - wg.x, dy = gy - wg.y;
            const float dist = sqrtf(dx * dx + dy * dy);
            const float s = (dist <= 7.5f) ? 1.f : 0.f;
            const float le = 250.f * s * fmaxf(1.f - dot, 0.f) + (1.f - s) * fmaxf(dot - 0.2f, 0.f);
            lsum += le * rm[q];
            out_dot[rowbase + q] = dot;
            out_s[rowbase + q] = s;
        }
        for (int k = 0;; ++k) {
            const int jj = l16 + (k << 4);
            if (jj >= s4) break;
            const int c = h + (jj << 2);
            const int q = cbase + c;
            const float4 dv = *reinterpret_cast<const float4*>(&Ds[row * 612 + 1 + c]);
            float sv[4];
            const float dd[4] = {dv.x, dv.y, dv.z, dv.w};
            #pragma unroll
            for (int u = 0; u < 4; ++u) {
                const float2 wg = wgrid[q + u];
                const float dx = gx - wg.x, dy = gy - wg.y;
                const float dist = sqrtf(dx * dx + dy * dy);
                const float s = (dist <= 7.5f) ? 1.f : 0.f;
                sv[u] = s;
                const float le = 250.f * s * fmaxf(1.f - dd[u], 0.f) + (1.f - s) * fmaxf(dd[u] - 0.2f, 0.f);
                lsum += le * rm[q + u];
            }
            *reinterpret_cast<float4*>(&out_dot[rowbase + q]) = dv;
            *reinterpret_cast<float4*>(&out_s[rowbase + q]) = make_float4(sv[0], sv[1], sv[2], sv[3]);
        }
        for (int c = ts + l16; c < W; c += 16) {
            const float dot = Ds[row * 612 + 1 + c];
            const int q = cbase + c;
            const float2 wg = wgrid[q];
            const float dx = gx - wg.x, dy = gy - wg.y;
            const float dist = sqrtf(dx * dx + dy * dy);
            const float s = (dist <= 7.5f) ? 1.f : 0.f;
            const float le = 250.f * s * fmaxf(1.f - dot, 0.f) + (1.f - s) * fmaxf(dot - 0.2f, 0.f);
            lsum += le * rm[q];
            out_dot[rowbase + q] = dot;
            out_s[rowbase + q] = s;
        }
        __syncthreads();   // protect Ds before next pass's compute
    }

    // ---- wave shuffle reduce, then 4-entry combine ----
    #pragma unroll
    for (int off = 32; off > 0; off >>= 1)
        lsum += __shfl_xor(lsum, off, 64);
    if (lane == 0) red[w] = lsum;
    __syncthreads();
    if (t == 0)
        partials[lid] = (red[0] + red[1]) + (red[2] + red[3]);
}

// ---------------- Kernel C: deterministic final reduction ----------------
__global__ __launch_bounds__(1024) void final_kernel(const float* __restrict__ partials,
                                                     const float* __restrict__ rmask,
                                                     float* __restrict__ out_loss) {
    __shared__ float red[1024];
    const int t = threadIdx.x;

    float s1 = 0.f;
    for (int i = t; i < NPART; i += 1024) s1 += partials[i];
    red[t] = s1;
    __syncthreads();
    for (int off = 512; off > 0; off >>= 1) {
        if (t < off) red[t] += red[t + off];
        __syncthreads();
    }
    float total = red[0];
    __syncthreads();

    float s2 = 0.f;
    for (int i = t; i < NB * MM; i += 1024) s2 += rmask[i];
    red[t] = s2;
    __syncthreads();
    for (int off = 512; off > 0; off >>= 1) {
        if (t < off) red[t] += red[t + off];
        __syncthreads();
    }
    if (t == 0) out_loss[0] = total / ((float)MM * red[0]);
}

extern "C" void kernel_launch(void* const* d_in, const int* in_sizes, int n_in,
                              void* d_out, int out_size, void* d_ws, size_t ws_size,
                              hipStream_t stream) {
    const float* des1 = (const float*)d_in[0];
    const float* des2 = (const float*)d_in[1];
    const float* homo = (const float*)d_in[2];
    const float* mask = (const float*)d_in[3];

    float* out      = (float*)d_out;
    float* out_loss = out;                                // 1
    float* out_s    = out + 1;                            // 11,520,000
    float* out_dot  = out + 1 + (size_t)NB * MM * MM;     // 11,520,000
    float* out_rm   = out + 1 + 2 * (size_t)NB * MM * MM; // 9,600

    // workspace layout (byte offsets, all 16B-aligned)
    char* wsb = (char*)d_ws;
    float2* wgrid    = (float2*)(wsb);                    //   9,600 B
    float*  partials = (float*)(wsb + 16384);             //   2,400 B
    float*  ws_rm    = (float*)(wsb + 32768);             //  38,400 B
    short*  wsA      = (short*)(wsb + 131072);            // 2,490,368 B
    short*  wsB      = wsA + (size_t)NB * PT * TILE_SH;   // 2,490,368 B

    dim3 cgrid(PT, 1, NB);
    convert_prep_kernel<<<cgrid, 256, 0, stream>>>(des1, des2, homo, mask,
                                                   wsA, wsB, wgrid, out_rm, ws_rm);

    main_kernel<<<dim3(NPART, 1, 1), 256, 0, stream>>>(wsA, wsB, wgrid, ws_rm,
                                                       out_s, out_dot, partials);

    final_kernel<<<1, 1024, 0, stream>>>(partials, ws_rm, out_loss);
}

// Round 6
// 46.535 us; speedup vs baseline: 1.0785x; 1.0785x over previous
//
#include <hip/hip_runtime.h>
#include <hip/hip_bf16.h>

#define HRr 30
#define WRr 40
#define MM 1200      // HRr*WRr
#define CC 128
#define NB 8
#define GS 8

constexpr int PT = 19;                   // 64-col fragment tiles per dim (ws layout)
constexpr int TILE_SH = 16 * 64 * 8;     // shorts per (n,tile) fragment block = 8192
constexpr int NPART = 1200;              // 8 images x 75 strips x 2 col-halves

typedef __attribute__((ext_vector_type(8))) short bf16x8;
typedef __attribute__((ext_vector_type(4))) float f32x4;

__device__ inline short f2bf(float f) {
    union { float f; unsigned u; } v; v.f = f;
    unsigned r = v.u + 0x7FFFu + ((v.u >> 16) & 1u);   // RNE
    return (short)(r >> 16);
}

// ------- Kernel A: fused {warped grid, reduced mask, f32->bf16 fragment convert} -------
// ws layout per (n, tile): [ks 0..3][rb 0..3][lane 0..63][8 halfwords]
// lane l = lr*16+lc holds (row = rb*16+lc, k = ks*32+lr*8 .. +7).
// Grid (PT, 4, NB): y splits the 16 k-runs 4-ways for 4x parallelism.
__global__ __launch_bounds__(256) void convert_prep_kernel(const float* __restrict__ des1,
                                                           const float* __restrict__ des2,
                                                           const float* __restrict__ homo,
                                                           const float* __restrict__ mask,
                                                           short* __restrict__ wsA,
                                                           short* __restrict__ wsB,
                                                           float2* __restrict__ wgrid,
                                                           float* __restrict__ out_rmask,
                                                           float* __restrict__ ws_rmask) {
    const int t     = threadIdx.x;
    const int ptile = blockIdx.x;      // 0..18
    const int n     = blockIdx.z;      // 0..7

    // ---- prep part (y==0 blocks; 152*256 = 38912 threads cover 9600) ----
    if (blockIdx.y == 0) {
        const int gid = (blockIdx.z * gridDim.x + blockIdx.x) * 256 + t;
        if (gid < MM) {
            int k = gid / WRr, l = gid % WRr;
            float x = (float)(l * GS + GS / 2);
            float y = (float)(k * GS + GS / 2);
            float nx = homo[0] * x + homo[1] * y + homo[2];
            float ny = homo[3] * x + homo[4] * y + homo[5];
            float dn = homo[6] * x + homo[7] * y + homo[8];
            wgrid[gid] = make_float2(nx / dn, ny / dn);
        }
        if (gid < NB * MM) {
            int nn = gid / MM;
            int rem = gid % MM;
            int k = rem / WRr, l = rem % WRr;
            const float* mp = mask + (size_t)nn * (240 * 320) + (size_t)(k * GS) * 320 + l * GS;
            float prod = 1.f;
            #pragma unroll
            for (int yy = 0; yy < GS; ++yy) {
                float4 a = *reinterpret_cast<const float4*>(&mp[yy * 320]);
                float4 b = *reinterpret_cast<const float4*>(&mp[yy * 320 + 4]);
                prod *= a.x * a.y * a.z * a.w * b.x * b.y * b.z * b.w;
            }
            out_rmask[gid] = prod;
            ws_rmask[gid]  = prod;
        }
    }

    // ---- convert part: this block handles k-runs kr = y*4 + wave ----
    const int j = t & 63;              // row within tile
    const int g = t >> 6;              // wave id
    const int p = ptile * 64 + j;

    const float* A = des1 + (size_t)n * CC * MM;
    const float* B = des2 + (size_t)n * CC * MM;
    short* outA = wsA + (size_t)(n * PT + ptile) * TILE_SH;
    short* outB = wsB + (size_t)(n * PT + ptile) * TILE_SH;

    const int rb = j >> 4, lc = j & 15;
    const int kr = blockIdx.y * 4 + g;      // k-run index 0..15
    const int kb = kr * 8;
    bf16x8 wa, wb;
    #pragma unroll
    for (int i = 0; i < 8; ++i) {
        float va = (p < MM) ? A[(size_t)(kb + i) * MM + p] : 0.f;  // coalesced per i
        float vb = (p < MM) ? B[(size_t)(kb + i) * MM + p] : 0.f;
        wa[i] = f2bf(va);
        wb[i] = f2bf(vb);
    }
    const int ks = kr >> 2, lr = kr & 3;
    const size_t off = (size_t)(((ks * 4 + rb) * 64) + lr * 16 + lc) * 8;
    *reinterpret_cast<bf16x8*>(&outA[off]) = wa;
    *reinterpret_cast<bf16x8*>(&outB[off]) = wb;
}

// ---------------- Kernel B: strip-half MFMA GEMM + line-aligned epilogue ----------------
// Block = (n, 16-row strip, col half). 1200 blocks; image n pinned to XCD n.
// Write phase: per-row head scalars to the 128B boundary, float4 body (full
// dirty lines, no write-allocate fetch), tail scalars.
__global__ __launch_bounds__(256) void main_kernel(const short* __restrict__ wsA,
                                                   const short* __restrict__ wsB,
                                                   const float2* __restrict__ wgrid,
                                                   const float* __restrict__ rmask,
                                                   float* __restrict__ out_s,
                                                   float* __restrict__ out_dot,
                                                   float* __restrict__ partials) {
    __shared__ float Ds[16 * 612];    // 16 rows x <=608 cols (+1 shift), stride 612 (2-way banks)
    __shared__ float red[4];

    const int f   = blockIdx.x;                      // 0..1199
    const int lid = (f & 7) * 150 + (f >> 3);        // image (f&7) -> XCD (f%8)
    const int n     = lid / 150;
    const int rem   = lid % 150;
    const int strip = rem >> 1;
    const int half  = rem & 1;
    const int p0    = strip * 16;
    const int cbase = half ? 608 : 0;
    const int nf    = half ? 37  : 38;    // col-frags this half
    const int W     = half ? 592 : 608;   // cols this half
    const int fbase = half ? 38  : 0;

    const int t    = threadIdx.x;
    const int lane = t & 63;
    const int w    = t >> 6;
    const int lr   = lane >> 4, lc = lane & 15;

    // A fragments for rows p0..p0+15, all 4 k-slices
    const short* An  = wsA + (size_t)(n * PT + (p0 >> 6)) * TILE_SH;
    const int    rbA = (p0 >> 4) & 3;
    bf16x8 af[4];
    #pragma unroll
    for (int ks = 0; ks < 4; ++ks)
        af[ks] = *reinterpret_cast<const bf16x8*>(&An[(size_t)(((ks * 4 + rbA) * 64) + lane) * 8]);

    const short* Bn = wsB + (size_t)n * PT * TILE_SH;
    const float* rm = rmask + n * MM;

    // ---- compute: each wave takes col-frags i = w, w+4, ... ----
    for (int i = w; i < nf; i += 4) {
        const int g = fbase + i;                       // global col-frag 0..74
        const short* Bt = Bn + (size_t)(g >> 2) * TILE_SH;
        const int rbB = g & 3;
        f32x4 acc = {0.f, 0.f, 0.f, 0.f};
        #pragma unroll
        for (int ks = 0; ks < 4; ++ks) {
            bf16x8 bfr = *reinterpret_cast<const bf16x8*>(
                &Bt[(size_t)(((ks * 4 + rbB) * 64) + lane) * 8]);
            acc = __builtin_amdgcn_mfma_f32_16x16x32_bf16(af[ks], bfr, acc, 0, 0, 0);
        }
        #pragma unroll
        for (int r = 0; r < 4; ++r)
            Ds[(lr * 4 + r) * 612 + 1 + i * 16 + lc] = acc[r];   // D row=lr*4+r, col=lc
    }
    __syncthreads();

    // ---- write phase: each 16-lane group owns one row ----
    const int row = t >> 4;
    const int l16 = t & 15;
    const int p   = p0 + row;
    const float gx = (float)((p % WRr) * GS + GS / 2);
    const float gy = (float)((p / WRr) * GS + GS / 2);
    const size_t rowbase = (size_t)(n * MM + p) * MM;
    const int h = 31 - 16 * (p & 1);   // cols to first 128B line boundary (incl. +1 buf offset)

    float lsum = 0.f;

    for (int c = l16; c < h; c += 16) {
        const float dot = Ds[row * 612 + 1 + c];
        const int q = cbase + c;
        const float2 wg = wgrid[q];
        const float dx = gx - wg.x, dy = gy - wg.y;
        const float dist = sqrtf(dx * dx + dy * dy);
        const float s = (dist <= 7.5f) ? 1.f : 0.f;
        const float le = 250.f * s * fmaxf(1.f - dot, 0.f) + (1.f - s) * fmaxf(dot - 0.2f, 0.f);
        lsum += le * rm[q];
        out_dot[rowbase + q] = dot;
        out_s[rowbase + q] = s;
    }
    const int nl = (W - h) >> 5;      // full 128B lines in body
    const int s4 = nl << 3;           // float4 slots
    const int ts = h + (nl << 5);     // tail start (rel col)
    for (int k = 0;; ++k) {
        const int jj = l16 + (k << 4);
        if (jj >= s4) break;
        const int c = h + (jj << 2);
        const int q = cbase + c;
        const float4 dv = *reinterpret_cast<const float4*>(&Ds[row * 612 + 1 + c]);
        float sv[4];
        const float dd[4] = {dv.x, dv.y, dv.z, dv.w};
        #pragma unroll
        for (int u = 0; u < 4; ++u) {
            const float2 wg = wgrid[q + u];
            const float dx = gx - wg.x, dy = gy - wg.y;
            const float dist = sqrtf(dx * dx + dy * dy);
            const float s = (dist <= 7.5f) ? 1.f : 0.f;
            sv[u] = s;
            const float le = 250.f * s * fmaxf(1.f - dd[u], 0.f) + (1.f - s) * fmaxf(dd[u] - 0.2f, 0.f);
            lsum += le * rm[q + u];
        }
        *reinterpret_cast<float4*>(&out_dot[rowbase + q]) = dv;
        *reinterpret_cast<float4*>(&out_s[rowbase + q]) = make_float4(sv[0], sv[1], sv[2], sv[3]);
    }
    for (int c = ts + l16; c < W; c += 16) {
        const float dot = Ds[row * 612 + 1 + c];
        const int q = cbase + c;
        const float2 wg = wgrid[q];
        const float dx = gx - wg.x, dy = gy - wg.y;
        const float dist = sqrtf(dx * dx + dy * dy);
        const float s = (dist <= 7.5f) ? 1.f : 0.f;
        const float le = 250.f * s * fmaxf(1.f - dot, 0.f) + (1.f - s) * fmaxf(dot - 0.2f, 0.f);
        lsum += le * rm[q];
        out_dot[rowbase + q] = dot;
        out_s[rowbase + q] = s;
    }

    // ---- wave shuffle reduce, then 4-entry combine ----
    #pragma unroll
    for (int off = 32; off > 0; off >>= 1)
        lsum += __shfl_xor(lsum, off, 64);
    if (lane == 0) red[w] = lsum;
    __syncthreads();
    if (t == 0)
        partials[lid] = (red[0] + red[1]) + (red[2] + red[3]);
}

// ---------------- Kernel C: deterministic final reduction ----------------
__global__ __launch_bounds__(1024) void final_kernel(const float* __restrict__ partials,
                                                     const float* __restrict__ rmask,
                                                     float* __restrict__ out_loss) {
    __shared__ float red[1024];
    const int t = threadIdx.x;

    float s1 = 0.f;
    for (int i = t; i < NPART; i += 1024) s1 += partials[i];
    red[t] = s1;
    __syncthreads();
    for (int off = 512; off > 0; off >>= 1) {
        if (t < off) red[t] += red[t + off];
        __syncthreads();
    }
    float total = red[0];
    __syncthreads();

    float s2 = 0.f;
    for (int i = t; i < NB * MM; i += 1024) s2 += rmask[i];
    red[t] = s2;
    __syncthreads();
    for (int off = 512; off > 0; off >>= 1) {
        if (t < off) red[t] += red[t + off];
        __syncthreads();
    }
    if (t == 0) out_loss[0] = total / ((float)MM * red[0]);
}

extern "C" void kernel_launch(void* const* d_in, const int* in_sizes, int n_in,
                              void* d_out, int out_size, void* d_ws, size_t ws_size,
                              hipStream_t stream) {
    const float* des1 = (const float*)d_in[0];
    const float* des2 = (const float*)d_in[1];
    const float* homo = (const float*)d_in[2];
    const float* mask = (const float*)d_in[3];

    float* out      = (float*)d_out;
    float* out_loss = out;                                // 1
    float* out_s    = out + 1;                            // 11,520,000
    float* out_dot  = out + 1 + (size_t)NB * MM * MM;     // 11,520,000
    float* out_rm   = out + 1 + 2 * (size_t)NB * MM * MM; // 9,600

    // workspace layout (byte offsets, all 16B-aligned)
    char* wsb = (char*)d_ws;
    float2* wgrid    = (float2*)(wsb);                    //   9,600 B
    float*  partials = (float*)(wsb + 16384);             //   4,800 B
    float*  ws_rm    = (float*)(wsb + 32768);             //  38,400 B
    short*  wsA      = (short*)(wsb + 131072);            // 2,490,368 B
    short*  wsB      = wsA + (size_t)NB * PT * TILE_SH;   // 2,490,368 B

    dim3 cgrid(PT, 4, NB);
    convert_prep_kernel<<<cgrid, 256, 0, stream>>>(des1, des2, homo, mask,
                                                   wsA, wsB, wgrid, out_rm, ws_rm);

    main_kernel<<<dim3(NPART, 1, 1), 256, 0, stream>>>(wsA, wsB, wgrid, ws_rm,
                                                       out_s, out_dot, partials);

    final_kernel<<<1, 1024, 0, stream>>>(partials, ws_rm, out_loss);
}